// Round 2
// baseline (62889.795 us; speedup 1.0000x reference)
//
#include <hip/hip_runtime.h>

typedef __attribute__((ext_vector_type(8))) short bh8;
typedef __attribute__((ext_vector_type(4))) float f32x4;
typedef __attribute__((ext_vector_type(4))) unsigned u32x4;

#define BATCH 16
#define SEQ 2048
#define M_ROWS (BATCH * SEQ)   // 32768
#define KDIM 1024

__device__ __forceinline__ unsigned short f2bf(float f) {
  unsigned u = __float_as_uint(f);
  u = (u + 0x7FFFu + ((u >> 16) & 1u)) >> 16;   // round-to-nearest-even
  return (unsigned short)u;
}
__device__ __forceinline__ float bf2f(unsigned short h) {
  return __uint_as_float(((unsigned)h) << 16);
}

__device__ __forceinline__ f32x4 mfma_bf16(bh8 a, bh8 b, f32x4 c) {
  return __builtin_amdgcn_mfma_f32_16x16x32_bf16(a, b, c, 0, 0, 0);
}

__device__ __forceinline__ void gl2lds16(const void* g, void* l) {
  __builtin_amdgcn_global_load_lds(
      (const __attribute__((address_space(1))) void*)g,
      (__attribute__((address_space(3))) void*)l, 16, 0, 0);
}

__global__ void cvt_bf16_kernel(const float* __restrict__ in,
                                unsigned short* __restrict__ out, int n4) {
  int i = blockIdx.x * blockDim.x + threadIdx.x;
  if (i >= n4) return;
  float4 v = ((const float4*)in)[i];
  ushort4 o;
  o.x = f2bf(v.x); o.y = f2bf(v.y); o.z = f2bf(v.z); o.w = f2bf(v.w);
  ((ushort4*)out)[i] = o;
}

__global__ void fill_ones_kernel(float* __restrict__ p, int n) {
  int i = blockIdx.x * blockDim.x + threadIdx.x;
  if (i < n) p[i] = 1.0f;
}

// C[M,N] = A[M,K] * B[N,K]^T   (A,B bf16 row-major, K = 1024)
// MODE 0: fp32 out + bias.  MODE 2: bf16 out, gi-permuted layout [s][slot32][g][b][dd32].
template<int MODE>
__global__ __launch_bounds__(256, 2) void gemm_nt(
    const unsigned short* __restrict__ A,
    const unsigned short* __restrict__ Bm,
    void* __restrict__ Cout,
    const float* __restrict__ bias,
    int N)
{
  __shared__ unsigned short As[128 * 32];
  __shared__ unsigned short Bs[128 * 32];
  const int tid = threadIdx.x;
  const int wave = tid >> 6, lane = tid & 63;
  const long tileM = (long)blockIdx.y * 128;
  const long tileN = (long)blockIdx.x * 128;

  const int srow = wave * 16 + (lane >> 2);
  const int scol = (lane & 3) * 8;
  const unsigned short* ga = A + (tileM + srow) * KDIM + scol;
  const unsigned short* gb = Bm + (tileN + srow) * KDIM + scol;
  unsigned short* la = As + wave * 512;
  unsigned short* lb = Bs + wave * 512;

  f32x4 acc[4][4];
  #pragma unroll
  for (int i = 0; i < 4; ++i)
    #pragma unroll
    for (int j = 0; j < 4; ++j)
      acc[i][j] = (f32x4){0.f, 0.f, 0.f, 0.f};

  const int wm = wave >> 1, wn = wave & 1;
  const int q = lane >> 4, mr = lane & 15;

  #pragma unroll 1
  for (int kt = 0; kt < 32; ++kt) {
    const int ko = kt * 32;
    gl2lds16(ga + ko, la);
    gl2lds16(ga + (long)64 * KDIM + ko, la + 2048);
    gl2lds16(gb + ko, lb);
    gl2lds16(gb + (long)64 * KDIM + ko, lb + 2048);
    __syncthreads();

    bh8 af[4], bfv[4];
    #pragma unroll
    for (int t = 0; t < 4; ++t)
      af[t] = *(const bh8*)&As[(wm * 64 + t * 16 + mr) * 32 + q * 8];
    #pragma unroll
    for (int t = 0; t < 4; ++t)
      bfv[t] = *(const bh8*)&Bs[(wn * 64 + t * 16 + mr) * 32 + q * 8];

    #pragma unroll
    for (int mt = 0; mt < 4; ++mt)
      #pragma unroll
      for (int nt = 0; nt < 4; ++nt)
        acc[mt][nt] = mfma_bf16(af[mt], bfv[nt], acc[mt][nt]);
    __syncthreads();
  }

  // C/D layout: col = lane&15, row = (lane>>4)*4 + reg
  #pragma unroll
  for (int mt = 0; mt < 4; ++mt) {
    #pragma unroll
    for (int nt = 0; nt < 4; ++nt) {
      long n = tileN + wn * 64 + nt * 16 + mr;
      #pragma unroll
      for (int i = 0; i < 4; ++i) {
        long m = tileM + wm * 64 + mt * 16 + q * 4 + i;
        if constexpr (MODE == 0) {
          ((float*)Cout)[m * N + n] = acc[mt][nt][i] + bias[n];
        } else {
          // permuted: m = b*2048+s ; n = g*1024 + slot*32 + dd
          int b = (int)(m >> 11), s = (int)(m & 2047);
          int g = (int)(n >> 10), sl = (int)((n >> 5) & 31), dd = (int)(n & 31);
          size_t idx = ((size_t)s * 32 + sl) * 1536 + (size_t)g * 512 + b * 32 + dd;
          ((unsigned short*)Cout)[idx] = f2bf(acc[mt][nt][i]);
        }
      }
    }
  }
}

// ============================================================================
// Persistent GRU, single-XCD edition.
//
// 256 WGs x 512 thr launched (>=1 WG/CU guaranteed co-resident: LB(512,2)
// caps VGPR at 256); each WG reads HW_REG_XCC_ID and registers in a per-XCD
// roster (agent atomics, one-time). First XCD to collect 32 WGs wins; its 32
// WGs run the GRU, the other 224 exit. h/flag transport uses sc0 (L1-bypass,
// L2-served) ops: within one XCD the shared L2 is the coherence point ->
// RT ~250 cy instead of ~2500 (cross-die LLC).
// Election is deadlock-free by pigeonhole (all 256 resident -> some XCD has
// >=32). Poll keeps a 1-in-256 agent-scope rescue read: a wrong sc0 theory
// fails absmax, never hangs.
// NOTE: all multi-load inline asm uses EARLY-CLOBBER outputs ("=&v") — the
// round-1 crash was the address pair being allocated on top of load 0's dst.
// ============================================================================
__global__ __launch_bounds__(512, 2) void gru_kernel(
    const unsigned short* __restrict__ gi,   // permuted [s][slot=32][g=3][b=16][dd=32] bf16
    const unsigned short* __restrict__ whh,  // [3072][1024] bf16
    const float* __restrict__ b_ih,
    const float* __restrict__ b_hh,
    unsigned* __restrict__ hdw,              // [2][8192] dwords = bf16 pairs, buf0 zeroed
    unsigned* __restrict__ flags,            // [32*16] flag dwords; +512: roster[8]+winner
    unsigned short* __restrict__ rnn,        // [M_ROWS][1024] bf16
    float* __restrict__ hidden_out)          // [16][1024] fp32
{
  const int tid = threadIdx.x;

  // ---- roster: discover placement, elect one XCD ----
  __shared__ unsigned sh_slot, sh_w;
  unsigned xcc;
  asm volatile("s_getreg_b32 %0, hwreg(HW_REG_XCC_ID)" : "=s"(xcc));
  xcc &= 7;
  unsigned* roster = flags + 512;
  if (tid == 0) {
    unsigned sl = __hip_atomic_fetch_add(&roster[xcc], 1u, __ATOMIC_RELAXED,
                                         __HIP_MEMORY_SCOPE_AGENT);
    if (sl == 31) {   // 32nd WG on this XCD -> claim winner (value = xcc+1)
      unsigned expct = 0;
      __hip_atomic_compare_exchange_strong(&roster[8], &expct, xcc + 1,
          __ATOMIC_RELAXED, __ATOMIC_RELAXED, __HIP_MEMORY_SCOPE_AGENT);
    }
    sh_slot = sl;
    unsigned w;
    do {
      w = __hip_atomic_load(&roster[8], __ATOMIC_RELAXED, __HIP_MEMORY_SCOPE_AGENT);
    } while (w == 0);
    sh_w = w;
  }
  __syncthreads();
  const unsigned slot = sh_slot;
  if (xcc + 1 != sh_w || slot >= 32) return;   // uniform exit: 224 WGs leave

  // ---- worker setup: 32 WGs, one per CU of the winning XCD ----
  const int wv = tid >> 6, lane = tid & 63;
  const int q = lane >> 4, nn = lane & 15;     // gather/MFMA role: nn=batch, q=k-sub
  const int D0 = (int)slot * 32;               // this WG's 32 output dims

  // persistent B-frags: wf[g][t][kk] covers cols D0+t*16+nn, k = wv*128+kk*32+q*8
  bh8 wf[3][2][4];
  #pragma unroll
  for (int g = 0; g < 3; ++g)
    #pragma unroll
    for (int t = 0; t < 2; ++t)
      #pragma unroll
      for (int kk = 0; kk < 4; ++kk) {
        int k = wv * 128 + kk * 32 + q * 8;
        wf[g][t][kk] = *(const bh8*)&whh[(size_t)(g * 1024 + D0 + t * 16 + nn) * 1024 + k];
      }

  const int b = tid >> 5, dd = tid & 31, d = D0 + dd;  // pointwise role
  const float bir = b_ih[d], biz = b_ih[1024 + d], bin_ = b_ih[2048 + d];
  const float bhr = b_hh[d], bhz = b_hh[1024 + d], bhn = b_hh[2048 + d];
  float hreg = 0.0f;

  __shared__ float red[8][3][2][16][17];   // +1 pad: breaks 4-way write conflict (~51 KB)

  // gi(0) prefetch (plain cached)
  const unsigned short* g0 = gi + (size_t)slot * 1536 + b * 32 + dd;
  unsigned short pg0 = g0[0], pg1 = g0[512], pg2 = g0[1024];

  #pragma unroll 1
  for (int s = 0; s < SEQ; ++s) {
    float gir = bf2f(pg0), giz = bf2f(pg1), gin = bf2f(pg2);

    // h(s) gather: 4x dwordx4 sc0 loads (bypass L1, served by this XCD's L2).
    // "=&v" early-clobber is REQUIRED: addr pair must not alias load dsts.
    const unsigned* hrow = hdw + (s & 1) * 8192 + nn * 512 + wv * 64 + q * 4;
    u32x4 tt[4];
    asm volatile(
        "global_load_dwordx4 %0, %4, off sc0\n\t"
        "global_load_dwordx4 %1, %4, off offset:64 sc0\n\t"
        "global_load_dwordx4 %2, %4, off offset:128 sc0\n\t"
        "global_load_dwordx4 %3, %4, off offset:192 sc0\n\t"
        "s_waitcnt vmcnt(0)"
        : "=&v"(tt[0]), "=&v"(tt[1]), "=&v"(tt[2]), "=&v"(tt[3])
        : "v"(hrow) : "memory");

    f32x4 acc[3][2];
    #pragma unroll
    for (int g = 0; g < 3; ++g)
      #pragma unroll
      for (int t = 0; t < 2; ++t)
        acc[g][t] = (f32x4){0.f, 0.f, 0.f, 0.f};

    #pragma unroll
    for (int kk = 0; kk < 4; ++kk) {
      union { u32x4 u4; bh8 v; } u;
      u.u4 = tt[kk];
      #pragma unroll
      for (int g = 0; g < 3; ++g)
        #pragma unroll
        for (int t = 0; t < 2; ++t)
          acc[g][t] = mfma_bf16(u.v, wf[g][t][kk], acc[g][t]);
    }

    // C layout: row=q*4+i (batch), col=nn (dim within 16-col tile t)
    #pragma unroll
    for (int g = 0; g < 3; ++g)
      #pragma unroll
      for (int t = 0; t < 2; ++t)
        #pragma unroll
        for (int i = 0; i < 4; ++i)
          red[wv][g][t][q * 4 + i][nn] = acc[g][t][i];
    __syncthreads();

    const int tt_ = dd >> 4, col = dd & 15;
    float ghr = 0.f, ghz = 0.f, ghn = 0.f;
    #pragma unroll
    for (int w8 = 0; w8 < 8; ++w8) {
      ghr += red[w8][0][tt_][b][col];
      ghz += red[w8][1][tt_][b][col];
      ghn += red[w8][2][tt_][b][col];
    }

    float xr = gir + bir + ghr + bhr;
    float xz = giz + biz + ghz + bhz;
    float r = 1.0f / (1.0f + __expf(-xr));
    float z = 1.0f / (1.0f + __expf(-xz));
    float u_ = gin + bin_ + r * (ghn + bhn);
    float e = __expf(-2.0f * fabsf(u_));
    float tnh = (1.0f - e) / (1.0f + e);
    float nv = copysignf(tnh, u_);
    hreg = (1.0f - z) * nv + z * hreg;

    unsigned short hb = f2bf(hreg);
    // publish h(s+1): pack bf16 pair (d, d^1) into one dword, even-dd lanes sc0-store
    unsigned hp = __shfl_xor((unsigned)hb, 1);
    if ((dd & 1) == 0) {
      unsigned val = ((unsigned)hb) | (hp << 16);
      const unsigned* ha = &hdw[((s + 1) & 1) * 8192 + b * 512 + ((unsigned)d >> 1)];
      asm volatile("global_store_dword %0, %1, off sc0" :: "v"(ha), "v"(val) : "memory");
    }

    rnn[((size_t)b * SEQ + s) * 1024 + d] = hb;   // plain cached store
    if (s == SEQ - 1) hidden_out[b * 1024 + d] = hreg;

    asm volatile("s_waitcnt vmcnt(0)" ::: "memory");  // h in L2 before barrier exit
    __syncthreads();

    if (tid == 0) {   // arrival flag, sc0 (L2-visible to all 32 WGs)
      unsigned sv = (unsigned)(s + 1);
      const unsigned* fa = &flags[slot * 16];
      asm volatile("global_store_dword %0, %1, off sc0" :: "v"(fa), "v"(sv) : "memory");
    }

    // gi(s+1) prefetch overlaps the spin window
    if (s + 1 < SEQ) {
      const unsigned short* gn = gi + ((size_t)(s + 1) * 32 + slot) * 1536 + b * 32 + dd;
      pg0 = gn[0]; pg1 = gn[512]; pg2 = gn[1024];
    }

    if (tid < 64) {   // wave0: lane-parallel poll of 32 flag lines (dup'd on hi lanes)
      const unsigned tgt = (unsigned)(s + 1);
      const unsigned* fp = &flags[(tid & 31) * 16];
      unsigned v; int spin = 0;
      do {
        if (((++spin) & 255) == 0) {
          v = __hip_atomic_load(fp, __ATOMIC_RELAXED, __HIP_MEMORY_SCOPE_AGENT);
        } else {
          asm volatile("global_load_dword %0, %1, off sc0\n\ts_waitcnt vmcnt(0)"
                       : "=&v"(v) : "v"(fp) : "memory");
        }
      } while (__ballot(v >= tgt) != ~0ull);
    }
    __syncthreads();
  }
}

extern "C" void kernel_launch(void* const* d_in, const int* in_sizes, int n_in,
                              void* d_out, int out_size, void* d_ws, size_t ws_size,
                              hipStream_t stream) {
  const float* x    = (const float*)d_in[0];
  // d_in[1..4] = attn weights — dead: softmax over a size-1 axis is identically 1.
  const float* w_ih = (const float*)d_in[5];
  const float* w_hh = (const float*)d_in[6];
  const float* b_ih = (const float*)d_in[7];
  const float* b_hh = (const float*)d_in[8];
  const float* fc_w = (const float*)d_in[9];
  const float* fc_b = (const float*)d_in[10];

  float* out        = (float*)d_out;                       // [16,2048,1024]
  float* hidden_out = out + (size_t)M_ROWS * 1024;         // [1,16,1024]
  float* attn_out   = hidden_out + 16 * 1024;              // [16,2048,1]

  char* ws = (char*)d_ws;
  unsigned short* x_bf   = (unsigned short*)(ws);                 // 67,108,864 B
  unsigned short* wih_bf = (unsigned short*)(ws + 67108864);      //  6,291,456
  unsigned short* whh_bf = (unsigned short*)(ws + 73400320);      //  6,291,456
  unsigned short* fcw_bf = (unsigned short*)(ws + 79691776);      //  2,097,152
  unsigned short* gi_bf  = (unsigned short*)(ws + 81788928);      // 201,326,592
  unsigned short* rnn_bf = (unsigned short*)(ws + 283115520);     // 67,108,864
  unsigned*       hdw    = (unsigned*)(ws + 350224384);           //     65,536
  unsigned*       flags  = (unsigned*)(ws + 350289920);           //      4,096 (flags+roster)

  hipMemsetAsync(hdw, 0, 65536 + 4096, stream);   // h(0)=0, flags=0, roster=0

  cvt_bf16_kernel<<<32768, 256, 0, stream>>>(x, x_bf, 8388608);
  cvt_bf16_kernel<<<3072, 256, 0, stream>>>(w_ih, wih_bf, 786432);
  cvt_bf16_kernel<<<3072, 256, 0, stream>>>(w_hh, whh_bf, 786432);
  cvt_bf16_kernel<<<1024, 256, 0, stream>>>(fc_w, fcw_bf, 262144);
  fill_ones_kernel<<<128, 256, 0, stream>>>(attn_out, 32768);

  // gi = x @ w_ih^T (bias deferred), bf16, permuted [s][slot=32][g][b][dd=32]
  gemm_nt<2><<<dim3(24, 256), 256, 0, stream>>>(x_bf, wih_bf, gi_bf, nullptr, 3072);

  // 256 WGs launched; 32 (one full XCD, elected at runtime) run the recurrence.
  gru_kernel<<<256, 512, 0, stream>>>(gi_bf, whh_bf, b_ih, b_hh, hdw, flags,
                                      rnn_bf, hidden_out);

  // output = rnn @ fc_w^T + fc_b, fp32 out
  gemm_nt<0><<<dim3(8, 256), 256, 0, stream>>>(rnn_bf, fcw_bf, out, fc_b, 1024);
}

// Round 3
// 13225.366 us; speedup vs baseline: 4.7552x; 4.7552x over previous
//
#include <hip/hip_runtime.h>

typedef __attribute__((ext_vector_type(8))) short bh8;
typedef __attribute__((ext_vector_type(4))) float f32x4;
typedef unsigned long long u64;

#define BATCH 16
#define SEQ 2048
#define M_ROWS (BATCH * SEQ)   // 32768
#define KDIM 1024

__device__ __forceinline__ unsigned short f2bf(float f) {
  unsigned u = __float_as_uint(f);
  u = (u + 0x7FFFu + ((u >> 16) & 1u)) >> 16;   // round-to-nearest-even
  return (unsigned short)u;
}
__device__ __forceinline__ float bf2f(unsigned short h) {
  return __uint_as_float(((unsigned)h) << 16);
}

__device__ __forceinline__ f32x4 mfma_bf16(bh8 a, bh8 b, f32x4 c) {
  return __builtin_amdgcn_mfma_f32_16x16x32_bf16(a, b, c, 0, 0, 0);
}

__device__ __forceinline__ void gl2lds16(const void* g, void* l) {
  __builtin_amdgcn_global_load_lds(
      (const __attribute__((address_space(1))) void*)g,
      (__attribute__((address_space(3))) void*)l, 16, 0, 0);
}

__global__ void cvt_bf16_kernel(const float* __restrict__ in,
                                unsigned short* __restrict__ out, int n4) {
  int i = blockIdx.x * blockDim.x + threadIdx.x;
  if (i >= n4) return;
  float4 v = ((const float4*)in)[i];
  ushort4 o;
  o.x = f2bf(v.x); o.y = f2bf(v.y); o.z = f2bf(v.z); o.w = f2bf(v.w);
  ((ushort4*)out)[i] = o;
}

__global__ void fill_ones_kernel(float* __restrict__ p, int n) {
  int i = blockIdx.x * blockDim.x + threadIdx.x;
  if (i < n) p[i] = 1.0f;
}

// C[M,N] = A[M,K] * B[N,K]^T   (A,B bf16 row-major, K = 1024)
// MODE 0: fp32 out + bias.  MODE 2: bf16 out, gi-permuted layout [s][wg64][g][b][dd16].
template<int MODE>
__global__ __launch_bounds__(256, 2) void gemm_nt(
    const unsigned short* __restrict__ A,
    const unsigned short* __restrict__ Bm,
    void* __restrict__ Cout,
    const float* __restrict__ bias,
    int N)
{
  __shared__ unsigned short As[128 * 32];
  __shared__ unsigned short Bs[128 * 32];
  const int tid = threadIdx.x;
  const int wave = tid >> 6, lane = tid & 63;
  const long tileM = (long)blockIdx.y * 128;
  const long tileN = (long)blockIdx.x * 128;

  const int srow = wave * 16 + (lane >> 2);
  const int scol = (lane & 3) * 8;
  const unsigned short* ga = A + (tileM + srow) * KDIM + scol;
  const unsigned short* gb = Bm + (tileN + srow) * KDIM + scol;
  unsigned short* la = As + wave * 512;
  unsigned short* lb = Bs + wave * 512;

  f32x4 acc[4][4];
  #pragma unroll
  for (int i = 0; i < 4; ++i)
    #pragma unroll
    for (int j = 0; j < 4; ++j)
      acc[i][j] = (f32x4){0.f, 0.f, 0.f, 0.f};

  const int wm = wave >> 1, wn = wave & 1;
  const int q = lane >> 4, mr = lane & 15;

  #pragma unroll 1
  for (int kt = 0; kt < 32; ++kt) {
    const int ko = kt * 32;
    gl2lds16(ga + ko, la);
    gl2lds16(ga + (long)64 * KDIM + ko, la + 2048);
    gl2lds16(gb + ko, lb);
    gl2lds16(gb + (long)64 * KDIM + ko, lb + 2048);
    __syncthreads();

    bh8 af[4], bfv[4];
    #pragma unroll
    for (int t = 0; t < 4; ++t)
      af[t] = *(const bh8*)&As[(wm * 64 + t * 16 + mr) * 32 + q * 8];
    #pragma unroll
    for (int t = 0; t < 4; ++t)
      bfv[t] = *(const bh8*)&Bs[(wn * 64 + t * 16 + mr) * 32 + q * 8];

    #pragma unroll
    for (int mt = 0; mt < 4; ++mt)
      #pragma unroll
      for (int nt = 0; nt < 4; ++nt)
        acc[mt][nt] = mfma_bf16(af[mt], bfv[nt], acc[mt][nt]);
    __syncthreads();
  }

  // C/D layout: col = lane&15, row = (lane>>4)*4 + reg
  #pragma unroll
  for (int mt = 0; mt < 4; ++mt) {
    #pragma unroll
    for (int nt = 0; nt < 4; ++nt) {
      long n = tileN + wn * 64 + nt * 16 + mr;
      #pragma unroll
      for (int i = 0; i < 4; ++i) {
        long m = tileM + wm * 64 + mt * 16 + q * 4 + i;
        if constexpr (MODE == 0) {
          ((float*)Cout)[m * N + n] = acc[mt][nt][i] + bias[n];
        } else {
          // permuted: m = b*2048+s ; n = g*1024 + wg*16 + dd
          int b = (int)(m >> 11), s = (int)(m & 2047);
          int g = (int)(n >> 10), wgi = (int)((n >> 4) & 63), dd = (int)(n & 15);
          size_t idx = ((size_t)s * 64 + wgi) * 768 + (size_t)g * 256 + b * 16 + dd;
          ((unsigned short*)Cout)[idx] = f2bf(acc[mt][nt][i]);
        }
      }
    }
  }
}

// ============================================================================
// Persistent GRU, 64 WGs x 256 threads — tag-carrying data packets.
//
// Old chain (10.5ms): publish + vmcnt(0) drain (RT1) -> flag store -> remote
// poll detect (RT2) -> h gather (RT3) = ~12.3K cy/step, all agent-scope LLC.
//
// New: h published as 8B packets {lo: 2x bf16, hi: tag = s+1} via relaxed
// agent-scope 8B atomic stores (single dwordx2 -> data+tag atomically
// visible). Readers poll-gather the DATA directly, accept when tag >= s.
// No flags, no drain, no global barrier: chain ~= 1-2 LLC RT.
//
// Safety: a WG enters iter s only after seeing all tags s, which requires
// every WG to have issued its iter-(s-1) publish — so nobody still needs
// buffer (s+1)&1's old generation when it's overwritten (2 buffers suffice),
// and tags are monotone so the poll can't deadlock (same agent-relaxed
// primitive the proven kernel polled with). Retries s_sleep-throttled
// (poll-storm lesson, R3 + round-2 regression). red[] is parity
// double-buffered -> single __syncthreads per step.
// ============================================================================
__global__ __launch_bounds__(256, 1) void gru_kernel(
    const unsigned short* __restrict__ gi,   // permuted [s][wg=64][g=3][b=16][dd=16] bf16
    const unsigned short* __restrict__ whh,  // [3072][1024] bf16
    const float* __restrict__ b_ih,
    const float* __restrict__ b_hh,
    u64* __restrict__ hq,                    // [2][16][512] tagged packets, zeroed
    unsigned short* __restrict__ rnn,        // [M_ROWS][1024] bf16
    float* __restrict__ hidden_out)          // [16][1024] fp32
{
  const int wg = blockIdx.x;
  const int tid = threadIdx.x;
  const int wv = tid >> 6, lane = tid & 63;
  const int D0 = wg * 16;
  const int q = lane >> 4, nn = lane & 15;   // gather/MFMA role: nn=batch, q=k-sub

  // persistent B-frags: B[k=wv*256+kk*32+q*8 ..][n=D0+nn] from w_hh
  bh8 wf[3][8];
  #pragma unroll
  for (int g = 0; g < 3; ++g)
    #pragma unroll
    for (int kk = 0; kk < 8; ++kk) {
      int k = wv * 256 + kk * 32 + q * 8;
      wf[g][kk] = *(const bh8*)&whh[(size_t)(g * 1024 + D0 + nn) * 1024 + k];
    }

  const int b = tid >> 4, dd = tid & 15, d = D0 + dd;  // pointwise role
  const float bir = b_ih[d], biz = b_ih[1024 + d], bin_ = b_ih[2048 + d];
  const float bhr = b_hh[d], bhz = b_hh[1024 + d], bhn = b_hh[2048 + d];
  float hreg = 0.0f;

  __shared__ float red[2][4][3][16][16];   // parity-doubled, 24 KB

  // gi(0) prefetch (plain cached)
  const unsigned short* g0 = gi + (size_t)wg * 768 + b * 16 + dd;
  unsigned short pg0 = g0[0], pg1 = g0[256], pg2 = g0[512];

  #pragma unroll 1
  for (int s = 0; s < SEQ; ++s) {
    const int par = s & 1;

    // ---- poll-gather h(s): 32 8B tagged packets per lane, accept tag >= s ----
    const u64* hrow = hq + par * 8192 + nn * 512 + wv * 128 + q * 4;
    u64 v[32];
    for (;;) {
      #pragma unroll
      for (int kk = 0; kk < 8; ++kk)
        #pragma unroll
        for (int j = 0; j < 4; ++j)
          v[kk * 4 + j] = __hip_atomic_load(&hrow[kk * 16 + j], __ATOMIC_RELAXED,
                                            __HIP_MEMORY_SCOPE_AGENT);
      unsigned mt = 0xffffffffu;
      #pragma unroll
      for (int i = 0; i < 32; ++i) {
        unsigned tg = (unsigned)(v[i] >> 32);
        mt = tg < mt ? tg : mt;
      }
      if (mt >= (unsigned)s) break;
      __builtin_amdgcn_s_sleep(2);   // throttle retries: don't storm the LLC
    }

    f32x4 acc0 = {0.f,0.f,0.f,0.f}, acc1 = {0.f,0.f,0.f,0.f}, acc2 = {0.f,0.f,0.f,0.f};
    #pragma unroll
    for (int kk = 0; kk < 8; ++kk) {
      union { unsigned w[4]; bh8 f; } u;
      u.w[0] = (unsigned)v[kk*4+0]; u.w[1] = (unsigned)v[kk*4+1];
      u.w[2] = (unsigned)v[kk*4+2]; u.w[3] = (unsigned)v[kk*4+3];
      acc0 = mfma_bf16(u.f, wf[0][kk], acc0);
      acc1 = mfma_bf16(u.f, wf[1][kk], acc1);
      acc2 = mfma_bf16(u.f, wf[2][kk], acc2);
    }
    #pragma unroll
    for (int i = 0; i < 4; ++i) {   // C: row=q*4+i (batch), col=nn (dim)
      red[par][wv][0][q * 4 + i][nn] = acc0[i];
      red[par][wv][1][q * 4 + i][nn] = acc1[i];
      red[par][wv][2][q * 4 + i][nn] = acc2[i];
    }
    __syncthreads();   // the ONLY barrier per step (red is parity-doubled)

    float ghr = red[par][0][0][b][dd] + red[par][1][0][b][dd]
              + red[par][2][0][b][dd] + red[par][3][0][b][dd];
    float ghz = red[par][0][1][b][dd] + red[par][1][1][b][dd]
              + red[par][2][1][b][dd] + red[par][3][1][b][dd];
    float ghn = red[par][0][2][b][dd] + red[par][1][2][b][dd]
              + red[par][2][2][b][dd] + red[par][3][2][b][dd];

    float gir = bf2f(pg0), giz = bf2f(pg1), gin = bf2f(pg2);
    float xr = gir + bir + ghr + bhr;
    float xz = giz + biz + ghz + bhz;
    float r = 1.0f / (1.0f + __expf(-xr));
    float z = 1.0f / (1.0f + __expf(-xz));
    float u_ = gin + bin_ + r * (ghn + bhn);
    float e = __expf(-2.0f * fabsf(u_));
    float tnh = (1.0f - e) / (1.0f + e);
    float nv = copysignf(tnh, u_);
    hreg = (1.0f - z) * nv + z * hreg;

    unsigned short hb = f2bf(hreg);
    // publish h(s+1): {2x bf16 (dims d, d^1), tag s+1} — fire & forget
    unsigned hp = __shfl_xor((unsigned)hb, 1);
    if ((dd & 1) == 0) {
      u64 pkt = (u64)(((unsigned)hb) | (hp << 16)) | ((u64)(unsigned)(s + 1) << 32);
      __hip_atomic_store(&hq[(par ^ 1) * 8192 + b * 512 + ((unsigned)d >> 1)], pkt,
                         __ATOMIC_RELAXED, __HIP_MEMORY_SCOPE_AGENT);
    }

    rnn[((size_t)b * SEQ + s) * 1024 + d] = hb;   // plain cached store
    if (s == SEQ - 1) hidden_out[b * 1024 + d] = hreg;

    // gi(s+1) prefetch overlaps the next gather's round trip
    if (s + 1 < SEQ) {
      const unsigned short* gn = gi + ((size_t)(s + 1) * 64 + wg) * 768 + b * 16 + dd;
      pg0 = gn[0]; pg1 = gn[256]; pg2 = gn[512];
    }
  }
}

extern "C" void kernel_launch(void* const* d_in, const int* in_sizes, int n_in,
                              void* d_out, int out_size, void* d_ws, size_t ws_size,
                              hipStream_t stream) {
  const float* x    = (const float*)d_in[0];
  // d_in[1..4] = attn weights — dead: softmax over a size-1 axis is identically 1.
  const float* w_ih = (const float*)d_in[5];
  const float* w_hh = (const float*)d_in[6];
  const float* b_ih = (const float*)d_in[7];
  const float* b_hh = (const float*)d_in[8];
  const float* fc_w = (const float*)d_in[9];
  const float* fc_b = (const float*)d_in[10];

  float* out        = (float*)d_out;                       // [16,2048,1024]
  float* hidden_out = out + (size_t)M_ROWS * 1024;         // [1,16,1024]
  float* attn_out   = hidden_out + 16 * 1024;              // [16,2048,1]

  char* ws = (char*)d_ws;
  unsigned short* x_bf   = (unsigned short*)(ws);                 // 67,108,864 B
  unsigned short* wih_bf = (unsigned short*)(ws + 67108864);      //  6,291,456
  unsigned short* whh_bf = (unsigned short*)(ws + 73400320);      //  6,291,456
  unsigned short* fcw_bf = (unsigned short*)(ws + 79691776);      //  2,097,152
  unsigned short* gi_bf  = (unsigned short*)(ws + 81788928);      // 201,326,592
  unsigned short* rnn_bf = (unsigned short*)(ws + 283115520);     // 67,108,864
  // hq (128 KB) OVERLAYS x_bf — x_bf is dead once gemm_nt<2> has consumed it;
  // the memset below is stream-ordered AFTER that GEMM. Footprint unchanged.
  u64*            hq     = (u64*)(ws);

  cvt_bf16_kernel<<<32768, 256, 0, stream>>>(x, x_bf, 8388608);
  cvt_bf16_kernel<<<3072, 256, 0, stream>>>(w_ih, wih_bf, 786432);
  cvt_bf16_kernel<<<3072, 256, 0, stream>>>(w_hh, whh_bf, 786432);
  cvt_bf16_kernel<<<1024, 256, 0, stream>>>(fc_w, fcw_bf, 262144);
  fill_ones_kernel<<<128, 256, 0, stream>>>(attn_out, 32768);

  // gi = x @ w_ih^T (bias deferred), bf16, permuted [s][wg64][g][b][dd16]
  gemm_nt<2><<<dim3(24, 256), 256, 0, stream>>>(x_bf, wih_bf, gi_bf, nullptr, 3072);

  // h(0)=0 with tag 0 in BOTH parity buffers (tags must reset every launch)
  hipMemsetAsync(hq, 0, 131072, stream);

  gru_kernel<<<64, 256, 0, stream>>>(gi_bf, whh_bf, b_ih, b_hh, hq,
                                     rnn_bf, hidden_out);

  // output = rnn @ fc_w^T + fc_b, fp32 out
  gemm_nt<0><<<dim3(8, 256), 256, 0, stream>>>(rnn_bf, fcw_bf, out, fc_b, 1024);
}